// Round 7
// baseline (342.637 us; speedup 1.0000x reference)
//
#include <hip/hip_runtime.h>

typedef __attribute__((ext_vector_type(8))) short bf16x8;
typedef __attribute__((ext_vector_type(4))) float f32x4;

#define NB    4096
#define NLINK 33
#define NJ    32
#define KTOT  1024
#define CJ    128

// Pre-converted, fragment-swizzled bf16 W (8.4 MB), rebuilt every call.
// Cell ((j*32 + kt)*128 + c)*4 + q holds bf16x8 of W[j][kt*32 + q*8 + e][c].
// (Layout correctness-verified R2-R6.)
__device__ short g_Wf[NJ * KTOT * CJ];

// round-to-nearest-even f32 -> bf16 (finite inputs)
static __device__ __forceinline__ short f2bf(float f) {
    unsigned u = __builtin_bit_cast(unsigned, f);
    unsigned r = u + 0x7FFFu + ((u >> 16) & 1u);
    return (short)(r >> 16);
}

__global__ __launch_bounds__(256) void conv_w(const float* __restrict__ W) {
    const int gid = blockIdx.x * 256 + threadIdx.x;
    const int q  = gid & 3;
    const int c  = (gid >> 2) & 127;
    const int kt = (gid >> 9) & 31;
    const int j  = gid >> 14;
    const float* src = W + ((size_t)j * KTOT + kt * 32 + q * 8) * CJ + c;
    bf16x8 v;
    #pragma unroll
    for (int e = 0; e < 8; ++e) v[e] = f2bf(src[(size_t)e * CJ]);
    reinterpret_cast<bf16x8*>(g_Wf)[gid] = v;
}

// Barrier-free, LDS-free grouped GEMM at high occupancy.
// Wave tile = 32 rows x 32 cols (acc 16 f32). 4 waves/block share one 32-col
// B band (L1 reuse), own disjoint 32-row slices. VGPR target ~85 -> 4 blk/CU.
__global__ __launch_bounds__(256, 4) void joint_gemm(
    const float* __restrict__ link,
    const float* __restrict__ jf,
    const float* __restrict__ bias,
    const int*   __restrict__ child,
    float* __restrict__ out)
{
    const int tid  = threadIdx.x;
    const int lane = tid & 63;
    const int wave = tid >> 6;       // row slice within block
    const int q    = lane >> 4;      // 0..3 (k-subgroup)
    const int r    = lane & 15;      // 0..15

    const int bx = blockIdx.x;
    const int j  = bx & 31;          // j-minor: 4 joint panels per XCD L2
    const int cb = (bx >> 5) & 3;    // 32-col band
    const int mt = bx >> 7;          // 128-row group
    const int cidx = child[j];

    const int row0 = mt * 128 + wave * 32;
    // A: lane (q,r) owns rows row0+r, row0+16+r at k-offset q*8
    const float* a0 = link + ((size_t)(row0 + r) * NLINK + cidx) * KTOT + q * 8;
    const float* a1 = a0 + (size_t)16 * NLINK * KTOT;

    const bf16x8* wb = reinterpret_cast<const bf16x8*>(g_Wf);
    const size_t bb = (size_t)j * 16384 + ((size_t)cb * 32 + r) * 4 + q;

    f32x4  acc[4] = {};              // [mi*2 + ni]
    float4 A0[2], A1[2];             // ping-pong A step buffers (raw f32)
    bf16x8 B0[2], B1[2];             // ping-pong B step buffers

    auto loadA = [&](float4* A, int ks) {
        A[0] = *reinterpret_cast<const float4*>(a0 + ks * 32);
        A[1] = *reinterpret_cast<const float4*>(a0 + ks * 32 + 4);
    };
    auto loadA2 = [&](float4* A, int ks) {
        A[0] = *reinterpret_cast<const float4*>(a1 + ks * 32);
        A[1] = *reinterpret_cast<const float4*>(a1 + ks * 32 + 4);
    };
    // buffers hold row r (elements 0..7) and row 16+r — pack as two pairs
    auto loadApair = [&](float4* A, int ks) {
        A[0] = *reinterpret_cast<const float4*>(a0 + ks * 32);
        A[1] = *reinterpret_cast<const float4*>(a1 + ks * 32);
        // second halves fetched in cvt via +4 loads? no — need all 8; use 4 float4
    };
    (void)loadA; (void)loadA2; (void)loadApair;

    // NOTE: each lane needs 8 floats of row r and 8 of row 16+r per step.
    float4 A0a[2], A0b[2], A1a[2], A1b[2];   // [0]=row r lo/hi? keep simple: a-row: 2 float4, b-row: 2 float4
    auto ldA = [&](float4* Ra, float4* Rb, int ks) {
        Ra[0] = *reinterpret_cast<const float4*>(a0 + ks * 32);
        Ra[1] = *reinterpret_cast<const float4*>(a0 + ks * 32 + 4);
        Rb[0] = *reinterpret_cast<const float4*>(a1 + ks * 32);
        Rb[1] = *reinterpret_cast<const float4*>(a1 + ks * 32 + 4);
    };
    auto ldB = [&](bf16x8* Bv, int ks) {
        Bv[0] = wb[bb + (size_t)ks * 512];
        Bv[1] = wb[bb + (size_t)ks * 512 + 64];
    };
    auto cvt = [&](const float4* Ra, const float4* Rb, bf16x8& f0, bf16x8& f1) {
        f0[0] = f2bf(Ra[0].x); f0[1] = f2bf(Ra[0].y); f0[2] = f2bf(Ra[0].z); f0[3] = f2bf(Ra[0].w);
        f0[4] = f2bf(Ra[1].x); f0[5] = f2bf(Ra[1].y); f0[6] = f2bf(Ra[1].z); f0[7] = f2bf(Ra[1].w);
        f1[0] = f2bf(Rb[0].x); f1[1] = f2bf(Rb[0].y); f1[2] = f2bf(Rb[0].z); f1[3] = f2bf(Rb[0].w);
        f1[4] = f2bf(Rb[1].x); f1[5] = f2bf(Rb[1].y); f1[6] = f2bf(Rb[1].z); f1[7] = f2bf(Rb[1].w);
    };

    ldA(A0a, A0b, 0); ldB(B0, 0);
    ldA(A1a, A1b, 1); ldB(B1, 1);

    #pragma unroll
    for (int g = 0; g < 16; ++g) {
        {   // ks = 2g : consume A0/B0, refill for 2g+2 (A before MFMA, B after)
            bf16x8 af0, af1;
            cvt(A0a, A0b, af0, af1);
            if (g < 15) ldA(A0a, A0b, 2 * g + 2);       // ~2-step HBM distance
            acc[0] = __builtin_amdgcn_mfma_f32_16x16x32_bf16(af0, B0[0], acc[0], 0, 0, 0);
            acc[1] = __builtin_amdgcn_mfma_f32_16x16x32_bf16(af0, B0[1], acc[1], 0, 0, 0);
            acc[2] = __builtin_amdgcn_mfma_f32_16x16x32_bf16(af1, B0[0], acc[2], 0, 0, 0);
            acc[3] = __builtin_amdgcn_mfma_f32_16x16x32_bf16(af1, B0[1], acc[3], 0, 0, 0);
            if (g < 15) ldB(B0, 2 * g + 2);             // L2 hits, ~1-step distance
        }
        {   // ks = 2g+1 : consume A1/B1, refill for 2g+3
            bf16x8 af0, af1;
            cvt(A1a, A1b, af0, af1);
            if (g < 15) ldA(A1a, A1b, 2 * g + 3);
            acc[0] = __builtin_amdgcn_mfma_f32_16x16x32_bf16(af0, B1[0], acc[0], 0, 0, 0);
            acc[1] = __builtin_amdgcn_mfma_f32_16x16x32_bf16(af0, B1[1], acc[1], 0, 0, 0);
            acc[2] = __builtin_amdgcn_mfma_f32_16x16x32_bf16(af1, B1[0], acc[2], 0, 0, 0);
            acc[3] = __builtin_amdgcn_mfma_f32_16x16x32_bf16(af1, B1[1], acc[3], 0, 0, 0);
            if (g < 15) ldB(B1, 2 * g + 3);
        }
    }

    // epilogue: + bias + joint_feats  (C layout: row = mi*16 + q*4 + rr, col = ni*16 + r)
    float bv[2];
    bv[0] = bias[j * CJ + cb * 32 + r];
    bv[1] = bias[j * CJ + cb * 32 + 16 + r];

    #pragma unroll
    for (int mi = 0; mi < 2; ++mi) {
        #pragma unroll
        for (int rr = 0; rr < 4; ++rr) {
            const int bg = row0 + mi * 16 + q * 4 + rr;
            const size_t ob = ((size_t)bg * NJ + j) * CJ + cb * 32;
            #pragma unroll
            for (int ni = 0; ni < 2; ++ni) {
                const int o = ni * 16 + r;
                out[ob + o] = acc[mi * 2 + ni][rr] + bv[ni] + jf[ob + o];
            }
        }
    }
}

extern "C" void kernel_launch(void* const* d_in, const int* in_sizes, int n_in,
                              void* d_out, int out_size, void* d_ws, size_t ws_size,
                              hipStream_t stream) {
    (void)in_sizes; (void)n_in; (void)out_size; (void)d_ws; (void)ws_size;
    const float* link  = (const float*)d_in[0];
    const float* jfeat = (const float*)d_in[1];
    const float* W     = (const float*)d_in[2];
    const float* bias  = (const float*)d_in[3];
    const int*   child = (const int*)d_in[4];
    float* out = (float*)d_out;

    conv_w<<<dim3((NJ * KTOT * CJ / 8) / 256), dim3(256), 0, stream>>>(W);
    // grid: j-minor (XCD panels), then 4 col-bands, then 32 row-groups
    joint_gemm<<<dim3(NJ * 4 * (NB / 128)), dim3(256), 0, stream>>>(link, jfeat, bias, child, out);
}

// Round 8
// 185.342 us; speedup vs baseline: 1.8487x; 1.8487x over previous
//
#include <hip/hip_runtime.h>

typedef __attribute__((ext_vector_type(8))) short bf16x8;
typedef __attribute__((ext_vector_type(4))) float f32x4;

#define NB    4096
#define NLINK 33
#define NJ    32
#define KTOT  1024
#define CJ    128
#define BM    128
#define BKF   32              // K floats per pipeline step
#define NT    (KTOT / BKF)    // 32 steps

// Pre-converted, fragment-swizzled bf16 W (8.4 MB), rebuilt every call.
// Cell ((j*32 + kt)*128 + c)*4 + q holds bf16x8 of W[j][kt*32 + q*8 + e][c].
// (Layout correctness-verified R2-R7.)
__device__ short g_Wf[NJ * KTOT * CJ];

// round-to-nearest-even f32 -> bf16 (finite inputs)
static __device__ __forceinline__ short f2bf(float f) {
    unsigned u = __builtin_bit_cast(unsigned, f);
    unsigned r = u + 0x7FFFu + ((u >> 16) & 1u);
    return (short)(r >> 16);
}

static __device__ __forceinline__ void gload_lds16(const void* g, void* l) {
    __builtin_amdgcn_global_load_lds(
        (const __attribute__((address_space(1))) void*)g,
        (__attribute__((address_space(3))) void*)l, 16, 0, 0);
}

__global__ __launch_bounds__(256) void conv_w(const float* __restrict__ W) {
    const int gid = blockIdx.x * 256 + threadIdx.x;
    const int q  = gid & 3;
    const int c  = (gid >> 2) & 127;
    const int kt = (gid >> 9) & 31;
    const int j  = gid >> 14;
    const float* src = W + ((size_t)j * KTOT + kt * 32 + q * 8) * CJ + c;
    bf16x8 v;
    #pragma unroll
    for (int e = 0; e < 8; ++e) v[e] = f2bf(src[(size_t)e * CJ]);
    reinterpret_cast<bf16x8*>(g_Wf)[gid] = v;
}

// Deep async pipeline: global_load_lds staging, counted vmcnt (never 0 in the
// main loop), raw s_barrier. 3 rotating LDS buffers; loads for 2 tiles always
// in flight per wave (12 x 1KB) -> queue never drains.
__global__ __launch_bounds__(256) void joint_gemm(
    const float* __restrict__ link,
    const float* __restrict__ jf,
    const float* __restrict__ bias,
    const int*   __restrict__ child,
    float* __restrict__ out)
{
    __shared__ float lA[3][BM * BKF];   // 3 x 16 KB, A tile in raw f32
    __shared__ short lB[3][512 * 8];    // 3 x 8 KB,  B tile (bf16 fragment cells)

    const int tid  = threadIdx.x;
    const int lane = tid & 63;
    const int wave = __builtin_amdgcn_readfirstlane(tid >> 6);  // 0..3, uniform
    const int wr   = wave >> 1;     // 64-row band
    const int wc   = wave & 1;      // 64-col band
    const int q    = lane >> 4;     // 0..3
    const int r    = lane & 15;     // 0..15

    const int j  = blockIdx.x & 31;    // j-minor: 4 joint panels per XCD L2
    const int mt = blockIdx.x >> 5;
    const int row0 = mt * BM;
    const int cidx = child[j];

    // ---- A staging geometry (both-sides swizzle, rule #21) ----
    // instr i covers rows wave*32+i*8+(lane>>3); LDS chunk slot s=lane&7 holds
    // global 16B chunk s ^ (row&7)  (row&7 == lane>>3 here).
    const int lrow   = lane >> 3;                  // 0..7
    const int schunk = (lane & 7) ^ lrow;          // swizzled source chunk
    const float* asrc[4];
    #pragma unroll
    for (int i = 0; i < 4; ++i)
        asrc[i] = link + ((size_t)(row0 + wave * 32 + i * 8 + lrow) * NLINK + cidx) * KTOT
                       + schunk * 4;

    // ---- B staging geometry ----
    // within each 64-cell group: LDS slot s holds source cell s ^ (s>>3)
    const int bslot_src = lane ^ ((lane >> 3) & 7);
    // read-side: lane (q,r) wants cell x=r*4+q of group (wc*4+ni): slot = x^(x>>3)
    const int blow = r * 4 + q;
    const int bsl  = blow ^ (blow >> 3);
    // A read-side swizzled chunk for k-floats [8q,8q+4)
    const int ch0 = (2 * q) ^ (r & 7);

    auto STAGE = [&](int t, int buf) {
        float* Ad = lA[buf] + wave * 32 * BKF;          // uniform per wave
        const int k0 = t * BKF;
        #pragma unroll
        for (int i = 0; i < 4; ++i)
            gload_lds16(asrc[i] + k0, Ad + i * 8 * BKF);
        #pragma unroll
        for (int i2 = 0; i2 < 2; ++i2) {
            const short* bsrc = g_Wf
                + ((size_t)((j * 32 + t) * 512 + wave * 128 + i2 * 64 + bslot_src)) * 8;
            short* Bd = lB[buf] + (wave * 128 + i2 * 64) * 8;
            gload_lds16(bsrc, Bd);
        }
    };

    f32x4 acc[4][4] = {};

    STAGE(0, 0);
    STAGE(1, 1);

    int cur = 0;
    for (int t = 0; t < NT; ++t) {
        if (t < NT - 1) asm volatile("s_waitcnt vmcnt(6)" ::: "memory");
        else            asm volatile("s_waitcnt vmcnt(0)" ::: "memory");
        __builtin_amdgcn_s_barrier();
        __builtin_amdgcn_sched_barrier(0);

        if (t + 2 < NT) STAGE(t + 2, cur == 0 ? 2 : cur - 1);   // buf (t+2)%3

        const f32x4*  Ar = reinterpret_cast<const f32x4*>(lA[cur]);
        const bf16x8* Br = reinterpret_cast<const bf16x8*>(lB[cur]);

        bf16x8 bf[4];
        #pragma unroll
        for (int ni = 0; ni < 4; ++ni) bf[ni] = Br[(wc * 4 + ni) * 64 + bsl];

        #pragma unroll
        for (int mi = 0; mi < 4; ++mi) {
            const int row = wr * 64 + mi * 16 + r;
            const f32x4 v0 = Ar[row * 8 + ch0];
            const f32x4 v1 = Ar[row * 8 + (ch0 ^ 1)];
            bf16x8 af;
            af[0] = f2bf(v0[0]); af[1] = f2bf(v0[1]); af[2] = f2bf(v0[2]); af[3] = f2bf(v0[3]);
            af[4] = f2bf(v1[0]); af[5] = f2bf(v1[1]); af[6] = f2bf(v1[2]); af[7] = f2bf(v1[3]);
            #pragma unroll
            for (int ni = 0; ni < 4; ++ni)
                acc[mi][ni] = __builtin_amdgcn_mfma_f32_16x16x32_bf16(af, bf[ni], acc[mi][ni], 0, 0, 0);
        }

        cur = (cur == 2) ? 0 : cur + 1;
    }

    // ---- epilogue: + bias + joint_feats ----
    float bv[4];
    #pragma unroll
    for (int ni = 0; ni < 4; ++ni) bv[ni] = bias[j * CJ + wc * 64 + ni * 16 + r];

    #pragma unroll
    for (int mi = 0; mi < 4; ++mi) {
        #pragma unroll
        for (int rr = 0; rr < 4; ++rr) {
            const int bg = row0 + wr * 64 + mi * 16 + q * 4 + rr;
            const size_t ob = ((size_t)bg * NJ + j) * CJ + wc * 64;
            #pragma unroll
            for (int ni = 0; ni < 4; ++ni) {
                const int o = ni * 16 + r;
                out[ob + o] = acc[mi][ni][rr] + bv[ni] + jf[ob + o];
            }
        }
    }
}

extern "C" void kernel_launch(void* const* d_in, const int* in_sizes, int n_in,
                              void* d_out, int out_size, void* d_ws, size_t ws_size,
                              hipStream_t stream) {
    (void)in_sizes; (void)n_in; (void)out_size; (void)d_ws; (void)ws_size;
    const float* link  = (const float*)d_in[0];
    const float* jfeat = (const float*)d_in[1];
    const float* W     = (const float*)d_in[2];
    const float* bias  = (const float*)d_in[3];
    const int*   child = (const int*)d_in[4];
    float* out = (float*)d_out;

    conv_w<<<dim3((NJ * KTOT * CJ / 8) / 256), dim3(256), 0, stream>>>(W);
    joint_gemm<<<dim3(NJ * (NB / BM)), dim3(256), 0, stream>>>(link, jfeat, bias, child, out);
}